// Round 11
// baseline (149.891 us; speedup 1.0000x reference)
//
#include <hip/hip_runtime.h>
#include <hip/hip_fp8.h>

#define C_ 512
#define T_ 2048
#define N_TOK 16384
#define K_CB 4096

typedef __attribute__((ext_vector_type(16))) float f32x16;

static __device__ __forceinline__ unsigned char f2fp8(float f) {
    __hip_fp8_e4m3 v(f);                 // OCP e4m3, RNE + saturate
    return (unsigned char)v.__x;
}

typedef const __attribute__((address_space(1))) void* gas_t;
typedef __attribute__((address_space(3))) void* las_t;
static __device__ __forceinline__ void stage16(const void* g, void* l) {
    __builtin_amdgcn_global_load_lds((gas_t)g, (las_t)l, 16, 0, 0);
}

// ---------------- Kernel 1: transpose student (B,C,T)->(N,C) fp8 + per-token partial stats ------
__global__ __launch_bounds__(256) void k1_prep(
    const float* __restrict__ student,   // (B,C,T) fp32
    const int* __restrict__ codes,       // (B,T) int32
    const float* __restrict__ codebook,  // (K,C) fp32
    unsigned char* __restrict__ A8,      // (N,C) fp8 out
    float* __restrict__ xnorm, float* __restrict__ dtg2)
{
    __shared__ float tile[64][65];
    __shared__ int lcodes[64];
    int tid = threadIdx.x;
    int tnum  = blockIdx.x >> 1;
    int chalf = blockIdx.x & 1;
    int b  = tnum >> 5;
    int t0 = (tnum & 31) << 6;
    int cbase = chalf << 8;             // 0 or 256
    int cx = tid & 63;                  // lane
    int q  = tid >> 6;                  // wave
    if (tid < 64) lcodes[tid] = codes[b * T_ + t0 + tid];
    __syncthreads();
    float ax2[16], ad2[16];
#pragma unroll
    for (int p = 0; p < 16; ++p) { ax2[p] = 0.f; ad2[p] = 0.f; }
    for (int c0 = cbase; c0 < cbase + 256; c0 += 64) {
#pragma unroll
        for (int p = 0; p < 16; ++p) {
            int ch = p * 4 + q;
            tile[ch][cx] = student[(size_t)b * (C_ * T_) + (size_t)(c0 + ch) * T_ + t0 + cx];
        }
        __syncthreads();
#pragma unroll
        for (int p = 0; p < 16; ++p) {
            int ty = p * 4 + q;
            float x = tile[cx][ty];
            int n = b * T_ + t0 + ty;
            A8[(size_t)n * C_ + c0 + cx] = f2fp8(x);
            ax2[p] += x * x;
            float cb = codebook[(size_t)lcodes[ty] * C_ + c0 + cx];
            float d = x - cb;
            ad2[p] += d * d;
        }
        __syncthreads();
    }
#pragma unroll
    for (int p = 0; p < 16; ++p) {
        float sx = ax2[p], sd = ad2[p];
#pragma unroll
        for (int m = 1; m < 64; m <<= 1) {
            sx += __shfl_xor(sx, m);
            sd += __shfl_xor(sd, m);
        }
        if (cx == 0) {
            int n = b * T_ + t0 + p * 4 + q;
            atomicAdd(&xnorm[n], sx);
            atomicAdd(&dtg2[n], sd);
        }
    }
}

// ---------------- Kernel 1b: codebook -> fp8 + row norms + init of all reduce buffers -----------
__global__ __launch_bounds__(256) void k1_cb(
    const float* __restrict__ codebook,
    unsigned char* __restrict__ B8,
    float* __restrict__ cbnorm,
    float* __restrict__ s_sum,
    unsigned* __restrict__ minpack,
    float* __restrict__ xnorm, float* __restrict__ dtg2,
    float* __restrict__ accum)
{
    int tid = threadIdx.x;
    int gidx = blockIdx.x * 256 + tid;
    if (gidx < N_TOK) {
        s_sum[gidx] = 0.f; minpack[gidx] = 0xFFFFFFFFu;
        xnorm[gidx] = 0.f; dtg2[gidx] = 0.f;
    }
    if (gidx < 8) accum[gidx] = 0.f;
    int lane = tid & 63;
    int w = tid >> 6;
    int row = blockIdx.x * 4 + w;
    const float* src = codebook + (size_t)row * C_ + lane * 8;
    float4 v0 = *(const float4*)(src);
    float4 v1 = *(const float4*)(src + 4);
    float s = v0.x*v0.x + v0.y*v0.y + v0.z*v0.z + v0.w*v0.w
            + v1.x*v1.x + v1.y*v1.y + v1.z*v1.z + v1.w*v1.w;
    unsigned lo = (unsigned)f2fp8(v0.x) | ((unsigned)f2fp8(v0.y) << 8)
                | ((unsigned)f2fp8(v0.z) << 16) | ((unsigned)f2fp8(v0.w) << 24);
    unsigned hi = (unsigned)f2fp8(v1.x) | ((unsigned)f2fp8(v1.y) << 8)
                | ((unsigned)f2fp8(v1.z) << 16) | ((unsigned)f2fp8(v1.w) << 24);
    *(uint2*)(B8 + (size_t)row * C_ + lane * 8) = make_uint2(lo, hi);
#pragma unroll
    for (int m = 1; m < 64; m <<= 1) s += __shfl_xor(s, m);
    if (lane == 0) cbnorm[row] = s;
}

// ---------------- Kernel 2: fraglin-A + streamed-B fp8 32x32 MFMA, pipelined epilogue -----------
// grid = 512 (256 row-strips x 2 col-halves, XCD-chunked); block = 512 (8 waves, 1x8 grid:
// wave = ALL 64 student rows x its own 32 cb-cols per cc).
// A (64x512 fp8 = 32KB) reg-staged ONCE into fragment-linear LDS [rt][m][lane^m] -> the 8
// A-reads/step are ds_read_b64 at base+(lane^m)*8 = conflict-free. B streamed 256x64B dbuf via
// global_load_lds (4-way conflicts, accepted). Epilogue of cc is pipelined over cc+1's 8 steps
// (ping-pong acc sets P/Q, 4 elems/step: trans-pipe work spreads instead of bursting).
__global__ __launch_bounds__(512, 4) void k2_main(
    const unsigned char* __restrict__ A8,
    const unsigned char* __restrict__ B8,
    const float* __restrict__ xnorm,
    const float* __restrict__ dtg2,
    const float* __restrict__ cbnorm,
    float* __restrict__ s_sum,
    unsigned* __restrict__ minpack)
{
    __shared__ __align__(16) unsigned char aL[32768];      // A fraglin: [rt2][m32][lane64][8B]
    __shared__ __align__(16) unsigned char bL[2][16384];   // B: 256 rows x 64B, dbuf
    __shared__ __align__(16) float cbL[2048];              // cbnorm for this col-half
    int tid = threadIdx.x;
    int lane = tid & 63;
    int wc = tid >> 6;                   // 0..7: wave owns cols [wc*32, wc*32+32) of each cc
    int l31 = lane & 31;
    int kh = lane >> 5;

    int orig = blockIdx.x;               // 512 = 8 XCD x 64
    int swz = (orig & 7) * 64 + (orig >> 3);
    int strip = swz >> 1;                // 0..255
    int chalf = swz & 1;
    int row0 = strip * 64;
    int cbase = chalf * 2048;

    // ---- stage A once, reg->LDS, fragment-linear with m-XOR lane swizzle ----
    // granule li: global row R=li>>5, k-slot M=li&31. dest lane-slot = kh*32 + ((R&31)^M).
#pragma unroll
    for (int i = 0; i < 4; ++i) {
        int li = i * 512 + tid;
        int R = li >> 5, M = li & 31;
        uint4 v = *(const uint4*)(A8 + (size_t)(row0 + R) * C_ + M * 16);
        char* base = (char*)aL + (R >> 5) * 16384 + M * 512;
        int lx = (R & 31) ^ M;
        *(uint2*)(base + lx * 8)       = make_uint2(v.x, v.y);   // kh = 0
        *(uint2*)(base + 256 + lx * 8) = make_uint2(v.z, v.w);   // kh = 1
    }
    // ---- stage cbnorm half once (2048 floats = 512 granules) ----
    stage16((const char*)cbnorm + (size_t)cbase * 4 + tid * 16, (char*)cbL + tid * 16);

#define STAGE_B(bi, tt_) do {                                                 \
        int cb0_ = cbase + ((tt_) >> 3) * 256;                                \
        int ko_ = ((tt_) & 7) * 64;                                           \
        _Pragma("unroll")                                                     \
        for (int i_ = 0; i_ < 2; ++i_) {                                      \
            int li_ = i_ * 512 + tid;                                         \
            int R_ = li_ >> 2;                                                \
            int G_ = (li_ & 3) ^ ((R_ >> 1) & 3);                             \
            stage16(B8 + (size_t)(cb0_ + R_) * C_ + ko_ + G_ * 16,            \
                    bL[bi] + li_ * 16);                                       \
        }                                                                     \
    } while (0)

    STAGE_B(0, 0);

    int myrow0 = row0 + l31, myrow1 = row0 + 32 + l31;
    float xn0 = xnorm[myrow0], xn1 = xnorm[myrow1];
    float dt0 = sqrtf(dtg2[myrow0]), dt1 = sqrtf(dtg2[myrow1]);
    float sv0 = 0.f, sv1 = 0.f;
    unsigned km0 = 0xFFFFFFFFu, km1 = 0xFFFFFFFFu;

    f32x16 accP0, accP1, accQ0, accQ1;   // ping-pong sets; [rt=0/1] each
#pragma unroll
    for (int r = 0; r < 16; ++r) { accP0[r]=0.f; accP1[r]=0.f; accQ0[r]=0.f; accQ1[r]=0.f; }

    int bR = wc * 32 + l31;              // B-tile row (cb col within cc)
    int bB = bR * 64 + kh * 8;
    int bx = (bR >> 1) & 3;
    int wlc = wc * 32 + 4 * kh;          // wave/lane's col base within a cc (local)
    int tt = 0;
    int epi_lc0 = 0;

    // One step: barrier; stage B(t+1); 8 free A-reads + 4 B-reads; 8 MFMA; 4-elem epi of prev cc.
#define CCSTEP(kt_, A0, A1, E0, E1, DOEPI)                                     \
    { __syncthreads();                                                         \
      if (tt < 63) STAGE_B((tt + 1) & 1, tt + 1);                              \
      const unsigned char* bT = bL[tt & 1];                                    \
      long aF0[4], aF1[4], bFv[4];                                             \
      _Pragma("unroll") for (int ksl = 0; ksl < 4; ++ksl) {                    \
          int m = (kt_) * 4 + ksl;                                             \
          int ao = m * 512 + ((lane ^ m) * 8);                                 \
          aF0[ksl] = *(const long*)((const char*)aL + ao);                     \
          aF1[ksl] = *(const long*)((const char*)aL + 16384 + ao);             \
          bFv[ksl] = *(const long*)(bT + bB + ((ksl ^ bx) * 16));              \
      }                                                                        \
      __builtin_amdgcn_s_setprio(1);                                           \
      _Pragma("unroll") for (int ksl = 0; ksl < 4; ++ksl) {                    \
          A0 = __builtin_amdgcn_mfma_f32_32x32x16_fp8_fp8(bFv[ksl], aF0[ksl], A0, 0, 0, 0); \
          A1 = __builtin_amdgcn_mfma_f32_32x32x16_fp8_fp8(bFv[ksl], aF1[ksl], A1, 0, 0, 0); \
      }                                                                        \
      __builtin_amdgcn_s_setprio(0);                                           \
      if (DOEPI) {                                                             \
          _Pragma("unroll") for (int j = 0; j < 2; ++j) {                      \
              int r = (kt_) * 2 + j;                                           \
              int lc = epi_lc0 + (r & 3) + 8 * (r >> 2);                       \
              float cbn = cbL[lc];                                             \
              float d0 = sqrtf(fmaxf(fmaf(-2.f, E0[r], xn0) + cbn, 0.f));      \
              sv0 += __expf(fminf(dt0 - d0, 80.f));                            \
              km0 = min(km0, (__float_as_uint(d0) & 0xFFFFF000u) | (unsigned)(cbase + lc)); \
              float d1 = sqrtf(fmaxf(fmaf(-2.f, E1[r], xn1) + cbn, 0.f));      \
              sv1 += __expf(fminf(dt1 - d1, 80.f));                            \
              km1 = min(km1, (__float_as_uint(d1) & 0xFFFFF000u) | (unsigned)(cbase + lc)); \
              E0[r] = 0.f; E1[r] = 0.f;                                        \
          }                                                                    \
      }                                                                        \
      ++tt; }

#define CC8(A0, A1, E0, E1, DOEPI)                                             \
    { _Pragma("unroll")                                                        \
      for (int kt = 0; kt < 8; ++kt) { CCSTEP(kt, A0, A1, E0, E1, DOEPI) } }

    CC8(accP0, accP1, accQ0, accQ1, false)                       // cc0 -> P
    epi_lc0 = 0 * 256 + wlc; CC8(accQ0, accQ1, accP0, accP1, true)   // cc1 -> Q, epi cc0
    epi_lc0 = 1 * 256 + wlc; CC8(accP0, accP1, accQ0, accQ1, true)   // cc2 -> P, epi cc1
    epi_lc0 = 2 * 256 + wlc; CC8(accQ0, accQ1, accP0, accP1, true)   // cc3 -> Q, epi cc2
    epi_lc0 = 3 * 256 + wlc; CC8(accP0, accP1, accQ0, accQ1, true)   // cc4 -> P, epi cc3
    epi_lc0 = 4 * 256 + wlc; CC8(accQ0, accQ1, accP0, accP1, true)   // cc5 -> Q, epi cc4
    epi_lc0 = 5 * 256 + wlc; CC8(accP0, accP1, accQ0, accQ1, true)   // cc6 -> P, epi cc5
    epi_lc0 = 6 * 256 + wlc; CC8(accQ0, accQ1, accP0, accP1, true)   // cc7 -> Q, epi cc6
#undef CC8
#undef CCSTEP
#undef STAGE_B

    // tail: epilogue of cc7 (Q)
    {
        int lcT = 7 * 256 + wlc;
#pragma unroll
        for (int r = 0; r < 16; ++r) {
            int lc = lcT + (r & 3) + 8 * (r >> 2);
            float cbn = cbL[lc];
            float d0 = sqrtf(fmaxf(fmaf(-2.f, accQ0[r], xn0) + cbn, 0.f));
            sv0 += __expf(fminf(dt0 - d0, 80.f));
            km0 = min(km0, (__float_as_uint(d0) & 0xFFFFF000u) | (unsigned)(cbase + lc));
            float d1 = sqrtf(fmaxf(fmaf(-2.f, accQ1[r], xn1) + cbn, 0.f));
            sv1 += __expf(fminf(dt1 - d1, 80.f));
            km1 = min(km1, (__float_as_uint(d1) & 0xFFFFF000u) | (unsigned)(cbase + lc));
        }
    }

    // merge k-halves (lane vs lane+32: same student rows, disjoint cb-col quads)
    sv0 += __shfl_xor(sv0, 32);
    sv1 += __shfl_xor(sv1, 32);
    km0 = min(km0, (unsigned)__shfl_xor((int)km0, 32));
    km1 = min(km1, (unsigned)__shfl_xor((int)km1, 32));
    if (lane < 32) {
        atomicAdd(&s_sum[myrow0], sv0);
        atomicMin(&minpack[myrow0], km0);
        atomicAdd(&s_sum[myrow1], sv1);
        atomicMin(&minpack[myrow1], km1);
    }
}

// ---------------- Kernel 3a: per-token CE/accuracy/emb-loss/target-dist reduce ----------------
__global__ __launch_bounds__(256) void k3a(
    const float* __restrict__ s_sum,
    const unsigned* __restrict__ minpack,
    const int* __restrict__ codes,
    const float* __restrict__ dtg2,
    float* __restrict__ accum)
{
    __shared__ float w0[4], w1[4], w2[4], w3[4];
    int tid = threadIdx.x;
    int n = blockIdx.x * 256 + tid;
    float ce = logf(s_sum[n]);           // = d_t + lse(-d) = per-token CE
    unsigned pred = minpack[n] & 0xFFFu; // col id in the low 12 bits
    float ok = (pred == (unsigned)codes[n]) ? 1.f : 0.f;
    float sq = dtg2[n];
    float td = sqrtf(sq);
#pragma unroll
    for (int m = 1; m < 64; m <<= 1) {
        ce += __shfl_xor(ce, m);
        ok += __shfl_xor(ok, m);
        sq += __shfl_xor(sq, m);
        td += __shfl_xor(td, m);
    }
    int lane = tid & 63, w = tid >> 6;
    if (lane == 0) { w0[w] = ce; w1[w] = ok; w2[w] = sq; w3[w] = td; }
    __syncthreads();
    if (tid == 0) {
        atomicAdd(&accum[0], w0[0] + w0[1] + w0[2] + w0[3]);
        atomicAdd(&accum[1], w1[0] + w1[1] + w1[2] + w1[3]);
        atomicAdd(&accum[2], w2[0] + w2[1] + w2[2] + w2[3]);
        atomicAdd(&accum[3], w3[0] + w3[1] + w3[2] + w3[3]);
    }
}

// ---------------- Kernel 3b: finalize 5 outputs ----------------
__global__ void k3b(const float* __restrict__ accum, float* __restrict__ out)
{
    if (threadIdx.x == 0 && blockIdx.x == 0) {
        float ce   = accum[0] / (float)N_TOK;
        float accy = accum[1] / (float)N_TOK;
        float emb  = accum[2] / ((float)N_TOK * (float)C_);
        float td   = accum[3] / (float)N_TOK;
        out[0] = emb + ce;   // total_loss (EMB_W=CE_W=1)
        out[1] = emb;        // emb_to_codebook_loss
        out[2] = ce;         // ce_loss
        out[3] = accy;       // token_accuracy
        out[4] = td;         // emb_to_target_dist
    }
}

extern "C" void kernel_launch(void* const* d_in, const int* in_sizes, int n_in,
                              void* d_out, int out_size, void* d_ws, size_t ws_size,
                              hipStream_t stream)
{
    const float* student  = (const float*)d_in[0];
    const int*   codes    = (const int*)d_in[1];
    const float* codebook = (const float*)d_in[2];
    // d_in[3] distance_matrix is unused by the reference.
    float* out = (float*)d_out;

    char* ws = (char*)d_ws;
    unsigned char* A8     = (unsigned char*)(ws);                  // 8 MiB
    unsigned char* B8     = (unsigned char*)(ws + 8388608);        // 2 MiB
    float* xnorm          = (float*)(ws + 10485760);               // 64 KiB
    float* dtg2           = (float*)(ws + 10551296);               // 64 KiB
    float* cbnorm         = (float*)(ws + 10616832);               // 16 KiB
    float* s_sum          = (float*)(ws + 10633216);               // 64 KiB
    unsigned* minpack     = (unsigned*)(ws + 10698752);            // 64 KiB
    float* accum          = (float*)(ws + 10829824);               // 64 B

    // k1_cb zero-inits s_sum/minpack/xnorm/dtg2/accum (stream-ordered before k1_prep's atomics)
    hipLaunchKernelGGL(k1_cb, dim3(1024), dim3(256), 0, stream,
                       codebook, B8, cbnorm, s_sum, minpack, xnorm, dtg2, accum);
    hipLaunchKernelGGL(k1_prep, dim3(512), dim3(256), 0, stream,
                       student, codes, codebook, A8, xnorm, dtg2);
    hipLaunchKernelGGL(k2_main, dim3(512), dim3(512), 0, stream,
                       A8, B8, xnorm, dtg2, cbnorm, s_sum, minpack);
    hipLaunchKernelGGL(k3a, dim3(64), dim3(256), 0, stream,
                       s_sum, minpack, codes, dtg2, accum);
    hipLaunchKernelGGL(k3b, dim3(1), dim3(64), 0, stream, accum, out);
}